// Round 6
// baseline (60.362 us; speedup 1.0000x reference)
//
#include <hip/hip_runtime.h>
#include <math.h>

// ASD between two 16384x3 fp32 point sets, uniform in [0,128)^3.
//
// R1-R4 (brute force O(N^2)): 96 -> 58.7 us, pinned at fp32 VALU issue roof.
// R5 (uniform-grid binning, 16^3 cells, counting sort, 3^3 scan + rigorous
//     expansion): 42.8 us -- but rocprof showed the in-graph hipMemsetAsync
//     became a fillBufferAligned node costing ~39 us/replay (fixed blit
//     overhead for a 32 KB fill). Compute itself is ~4 us.
// R6: (a) replace memset with a tiny init kernel; (b) fuse the final sum
//     into nn_kernel via u64 fixed-point atomicAdd (associative -> bit-
//     deterministic) + done-counter, dropping sum_kernel. 5 plain compute
//     nodes, no blit.
//
// Determinism: scatter order within a cell is atomic-order-dependent, but a
// cell's point SET is fixed -> min over it is order-independent. Block
// partials are fixed-order trees; cross-block sum is integer (associative).

#define NPTS     16384
#define G        16
#define NC       (G * G * G)       // 4096 cells
#define CELL     8.0f
#define INV_CELL 0.125f
#define FIXSCALE 1048576.0         // 2^20 fixed-point for the global sum

// ws layout (u32 index):            bytes
//  hist [2][NC]          @ 0        32768
//  off  [2][NC+1]        @ 8192     32776
//  cur  [2][NC]          @ 16896    32768
//  srt  [2][NPTS] float4 @ 25088    524288   (byte 100352, 16B aligned)
//  total u64             @ 156160   8        (byte 624640, 8B aligned)
//  done  u32             @ 156162   4        -> total 624652 B < 1 MiB
#define W_HIST  0
#define W_OFF   8192
#define W_CUR   16896
#define W_SRT   25088
#define W_TOTAL 156160
#define W_DONE  156162

__device__ __forceinline__ int clampi(int v, int lo, int hi) {
    return v < lo ? lo : (v > hi ? hi : v);
}

__device__ __forceinline__ int cell_of(float x, float y, float z) {
    const int cx = clampi((int)(x * INV_CELL), 0, G - 1);
    const int cy = clampi((int)(y * INV_CELL), 0, G - 1);
    const int cz = clampi((int)(z * INV_CELL), 0, G - 1);
    return (cz * G + cy) * G + cx;
}

__global__ __launch_bounds__(256) void init_kernel(unsigned* __restrict__ W)
{
    const int g = blockIdx.x * 256 + threadIdx.x;     // 8192 threads
    W[W_HIST + g] = 0u;                               // zero both histograms
    if (g < 3) W[W_TOTAL + g] = 0u;                   // total(2 words) + done
}

__global__ __launch_bounds__(256) void hist_kernel(
    const float* __restrict__ real, const float* __restrict__ pred,
    unsigned* __restrict__ hist)
{
    const int g   = blockIdx.x * 256 + threadIdx.x;   // 0..32767
    const int set = g >> 14;
    const int i   = g & (NPTS - 1);
    const float* __restrict__ p = set ? pred : real;  // set0=real, set1=pred
    const float x = p[3 * i], y = p[3 * i + 1], z = p[3 * i + 2];
    atomicAdd(&hist[set * NC + cell_of(x, y, z)], 1u);
}

// Dual exclusive scan of hist[0][0..NC) and hist[1][0..NC) in one block.
__global__ __launch_bounds__(1024) void scan_kernel(
    const unsigned* __restrict__ hist,
    unsigned* __restrict__ off, unsigned* __restrict__ cur)
{
    const int tid  = threadIdx.x;
    const int lane = tid & 63;
    const int wave = tid >> 6;
    const int base = tid * 4;                          // 4 elements per thread

    unsigned a0[4], a1[4], s0 = 0, s1 = 0;
#pragma unroll
    for (int j = 0; j < 4; ++j) {
        a0[j] = hist[base + j];        s0 += a0[j];
        a1[j] = hist[NC + base + j];   s1 += a1[j];
    }

    unsigned i0 = s0, i1 = s1;                         // inclusive wave scan
#pragma unroll
    for (int d = 1; d < 64; d <<= 1) {
        const unsigned t0 = __shfl_up(i0, d, 64);
        const unsigned t1 = __shfl_up(i1, d, 64);
        if (lane >= d) { i0 += t0; i1 += t1; }
    }

    __shared__ unsigned w0[16], w1[16];
    if (lane == 63) { w0[wave] = i0; w1[wave] = i1; }
    __syncthreads();
    if (tid == 0) {                                    // scan 16 wave totals
        unsigned r0 = 0, r1 = 0;
        for (int w = 0; w < 16; ++w) {
            const unsigned t0 = w0[w]; w0[w] = r0; r0 += t0;
            const unsigned t1 = w1[w]; w1[w] = r1; r1 += t1;
        }
    }
    __syncthreads();

    unsigned e0 = w0[wave] + (i0 - s0);                // thread-exclusive prefix
    unsigned e1 = w1[wave] + (i1 - s1);
#pragma unroll
    for (int j = 0; j < 4; ++j) {
        off[base + j]            = e0;
        cur[base + j]            = e0;
        off[(NC + 1) + base + j] = e1;
        cur[NC + base + j]       = e1;
        e0 += a0[j];
        e1 += a1[j];
    }
    if (tid == 0) { off[NC] = NPTS; off[(NC + 1) + NC] = NPTS; }
}

__global__ __launch_bounds__(256) void scatter_kernel(
    const float* __restrict__ real, const float* __restrict__ pred,
    unsigned* __restrict__ cur, float4* __restrict__ srt)
{
    const int g   = blockIdx.x * 256 + threadIdx.x;
    const int set = g >> 14;
    const int i   = g & (NPTS - 1);
    const float* __restrict__ p = set ? pred : real;
    const float x = p[3 * i], y = p[3 * i + 1], z = p[3 * i + 2];
    const unsigned pos = atomicAdd(&cur[set * NC + cell_of(x, y, z)], 1u);
    srt[set * NPTS + pos] = make_float4(x, y, z, 0.0f);
}

// 8 lanes per query. dir0 (g<16384): query=pred[g], refs=sorted real (set0).
// dir1: query=real[g-16384], refs=sorted pred (set1). Final sum fused via
// u64 fixed-point atomics + done-counter (deterministic).
__global__ __launch_bounds__(256) void nn_kernel(
    const float* __restrict__ real, const float* __restrict__ pred,
    const unsigned* __restrict__ off, const float4* __restrict__ srt,
    unsigned long long* __restrict__ total, unsigned* __restrict__ done,
    float* __restrict__ out)
{
    const int tid   = threadIdx.x;
    const int lane8 = tid & 7;
    const int g     = blockIdx.x * 32 + (tid >> 3);   // 0..32767
    const int dir   = g >> 14;
    const int qi    = g & (NPTS - 1);

    const float* __restrict__ qp      = dir ? real : pred;
    const unsigned* __restrict__ offr = off + dir * (NC + 1);
    const float4* __restrict__ refs   = srt + dir * NPTS;

    const float qx = qp[3 * qi], qy = qp[3 * qi + 1], qz = qp[3 * qi + 2];
    const int qcx = clampi((int)(qx * INV_CELL), 0, G - 1);
    const int qcy = clampi((int)(qy * INV_CELL), 0, G - 1);
    const int qcz = clampi((int)(qz * INV_CELL), 0, G - 1);

    float best = INFINITY;
    int k = 1;
    for (;;) {
        float b = INFINITY;
        const int z0 = clampi(qcz - k, 0, G - 1), z1 = clampi(qcz + k, 0, G - 1);
        const int y0 = clampi(qcy - k, 0, G - 1), y1 = clampi(qcy + k, 0, G - 1);
        const int x0 = clampi(qcx - k, 0, G - 1), x1 = clampi(qcx + k, 0, G - 1);
        for (int cz = z0; cz <= z1; ++cz) {
            for (int cy = y0; cy <= y1; ++cy) {
                const int rowc = (cz * G + cy) * G;
                for (int cx = x0; cx <= x1; ++cx) {
                    const int c = rowc + cx;
                    const unsigned s = offr[c];
                    const unsigned e = offr[c + 1];
                    for (unsigned i = s + lane8; i < e; i += 8) {
                        const float4 r = refs[i];
                        const float dx = qx - r.x;
                        const float dy = qy - r.y;
                        const float dz = qz - r.z;
                        b = fminf(b, fmaf(dx, dx, fmaf(dy, dy, dz * dz)));
                    }
                }
            }
        }
        // 8-lane group min (bits 0..2 stay inside the group).
        b = fminf(b, __shfl_xor(b, 1, 64));
        b = fminf(b, __shfl_xor(b, 2, 64));
        b = fminf(b, __shfl_xor(b, 4, 64));
        best = fminf(best, b);
        const float reach = CELL * (float)k;
        if (best <= reach * reach || k >= G) break;   // outside pts are > 8k away
        ++k;                                          // expand (P ~ 6e-8/query)
    }

    // Deterministic per-block partial sum of sqrt(best) over 32 groups,
    // then one u64 fixed-point atomic per block.
    __shared__ float gs[32];
    if (lane8 == 0) gs[tid >> 3] = sqrtf(best);
    __syncthreads();
    if (tid == 0) {
        float s = 0.0f;
        for (int j = 0; j < 32; ++j) s += gs[j];
        const unsigned long long q =
            (unsigned long long)((double)s * FIXSCALE + 0.5);
        atomicAdd(total, q);
        __threadfence();                              // publish before done++
        const unsigned prev = atomicAdd(done, 1u);
        if (prev == gridDim.x - 1) {                  // last block finalizes
            __threadfence();
            const unsigned long long t = atomicAdd(total, 0ULL);
            out[0] = (float)((double)t / FIXSCALE / (double)(2 * NPTS));
        }
    }
}

extern "C" void kernel_launch(void* const* d_in, const int* in_sizes, int n_in,
                              void* d_out, int out_size, void* d_ws, size_t ws_size,
                              hipStream_t stream)
{
    const float* real_pts = (const float*)d_in[0];
    const float* pred_pts = (const float*)d_in[1];
    float* out = (float*)d_out;
    unsigned* W = (unsigned*)d_ws;

    unsigned* hist = W + W_HIST;
    unsigned* off  = W + W_OFF;
    unsigned* cur  = W + W_CUR;
    float4*   srt  = (float4*)(W + W_SRT);
    unsigned long long* total = (unsigned long long*)(W + W_TOTAL);
    unsigned* done = W + W_DONE;

    init_kernel   <<<2 * NC / 256, 256, 0, stream>>>(W);
    hist_kernel   <<<2 * NPTS / 256, 256, 0, stream>>>(real_pts, pred_pts, hist);
    scan_kernel   <<<1, 1024, 0, stream>>>(hist, off, cur);
    scatter_kernel<<<2 * NPTS / 256, 256, 0, stream>>>(real_pts, pred_pts, cur, srt);
    nn_kernel     <<<2 * NPTS / 32, 256, 0, stream>>>(real_pts, pred_pts, off, srt,
                                                      total, done, out);
}

// Round 7
// 42.648 us; speedup vs baseline: 1.4154x; 1.4154x over previous
//
#include <hip/hip_runtime.h>
#include <math.h>

// ASD between two 16384x3 fp32 point sets, uniform in [0,128)^3.
//
// R1-R4 (brute force O(N^2)): 96 -> 58.7 us, pinned at fp32 VALU issue roof.
// R5 (uniform-grid binning): 42.8 us; in-graph hipMemsetAsync became a
//     fillBufferAligned node costing ~39 us/replay. Compute itself ~4 us.
// R6: replaced memset with init_kernel (good) BUT fused the final sum into
//     nn_kernel with u64 atomics + __threadfence: the device-scope fence
//     (L2 writeback, cross-XCD) from 1024 blocks cost ~43 us -- nn_kernel
//     46 us even with warm caches. Lesson: fences and blits ~40 us here;
//     plain compute dispatches ~1 us.
// R7: revert to R5's separate 1-block sum_kernel (fixed-order trees, no
//     fences, no float atomics), keep init_kernel. 6 plain compute nodes.
//
// Determinism: scatter order within a cell is atomic-order-dependent, but a
// cell's point SET is fixed -> min over it is order-independent. All sums
// are fixed-order trees. Same input -> bit-identical output.

#define NPTS     16384
#define G        16
#define NC       (G * G * G)       // 4096 cells
#define CELL     8.0f
#define INV_CELL 0.125f

// ws layout (u32 index):            bytes
//  hist [2][NC]          @ 0        32768
//  off  [2][NC+1]        @ 8192     32776
//  cur  [2][NC]          @ 16896    32768
//  srt  [2][NPTS] float4 @ 25088    524288   (byte 100352, 16B aligned)
//  bsum [1024]  float    @ 156160   4096     -> total < 1 MiB
#define W_HIST 0
#define W_OFF  8192
#define W_CUR  16896
#define W_SRT  25088
#define W_BSUM 156160

__device__ __forceinline__ int clampi(int v, int lo, int hi) {
    return v < lo ? lo : (v > hi ? hi : v);
}

__device__ __forceinline__ int cell_of(float x, float y, float z) {
    const int cx = clampi((int)(x * INV_CELL), 0, G - 1);
    const int cy = clampi((int)(y * INV_CELL), 0, G - 1);
    const int cz = clampi((int)(z * INV_CELL), 0, G - 1);
    return (cz * G + cy) * G + cx;
}

__global__ __launch_bounds__(256) void init_kernel(unsigned* __restrict__ W)
{
    const int g = blockIdx.x * 256 + threadIdx.x;     // 8192 threads
    W[W_HIST + g] = 0u;                               // zero both histograms
}

__global__ __launch_bounds__(256) void hist_kernel(
    const float* __restrict__ real, const float* __restrict__ pred,
    unsigned* __restrict__ hist)
{
    const int g   = blockIdx.x * 256 + threadIdx.x;   // 0..32767
    const int set = g >> 14;
    const int i   = g & (NPTS - 1);
    const float* __restrict__ p = set ? pred : real;  // set0=real, set1=pred
    const float x = p[3 * i], y = p[3 * i + 1], z = p[3 * i + 2];
    atomicAdd(&hist[set * NC + cell_of(x, y, z)], 1u);
}

// Dual exclusive scan of hist[0][0..NC) and hist[1][0..NC) in one block.
__global__ __launch_bounds__(1024) void scan_kernel(
    const unsigned* __restrict__ hist,
    unsigned* __restrict__ off, unsigned* __restrict__ cur)
{
    const int tid  = threadIdx.x;
    const int lane = tid & 63;
    const int wave = tid >> 6;
    const int base = tid * 4;                          // 4 elements per thread

    unsigned a0[4], a1[4], s0 = 0, s1 = 0;
#pragma unroll
    for (int j = 0; j < 4; ++j) {
        a0[j] = hist[base + j];        s0 += a0[j];
        a1[j] = hist[NC + base + j];   s1 += a1[j];
    }

    unsigned i0 = s0, i1 = s1;                         // inclusive wave scan
#pragma unroll
    for (int d = 1; d < 64; d <<= 1) {
        const unsigned t0 = __shfl_up(i0, d, 64);
        const unsigned t1 = __shfl_up(i1, d, 64);
        if (lane >= d) { i0 += t0; i1 += t1; }
    }

    __shared__ unsigned w0[16], w1[16];
    if (lane == 63) { w0[wave] = i0; w1[wave] = i1; }
    __syncthreads();
    if (tid == 0) {                                    // scan 16 wave totals
        unsigned r0 = 0, r1 = 0;
        for (int w = 0; w < 16; ++w) {
            const unsigned t0 = w0[w]; w0[w] = r0; r0 += t0;
            const unsigned t1 = w1[w]; w1[w] = r1; r1 += t1;
        }
    }
    __syncthreads();

    unsigned e0 = w0[wave] + (i0 - s0);                // thread-exclusive prefix
    unsigned e1 = w1[wave] + (i1 - s1);
#pragma unroll
    for (int j = 0; j < 4; ++j) {
        off[base + j]            = e0;
        cur[base + j]            = e0;
        off[(NC + 1) + base + j] = e1;
        cur[NC + base + j]       = e1;
        e0 += a0[j];
        e1 += a1[j];
    }
    if (tid == 0) { off[NC] = NPTS; off[(NC + 1) + NC] = NPTS; }
}

__global__ __launch_bounds__(256) void scatter_kernel(
    const float* __restrict__ real, const float* __restrict__ pred,
    unsigned* __restrict__ cur, float4* __restrict__ srt)
{
    const int g   = blockIdx.x * 256 + threadIdx.x;
    const int set = g >> 14;
    const int i   = g & (NPTS - 1);
    const float* __restrict__ p = set ? pred : real;
    const float x = p[3 * i], y = p[3 * i + 1], z = p[3 * i + 2];
    const unsigned pos = atomicAdd(&cur[set * NC + cell_of(x, y, z)], 1u);
    srt[set * NPTS + pos] = make_float4(x, y, z, 0.0f);
}

// 8 lanes per query. dir0 (g<16384): query=pred[g], refs=sorted real (set0).
// dir1: query=real[g-16384], refs=sorted pred (set1).
__global__ __launch_bounds__(256) void nn_kernel(
    const float* __restrict__ real, const float* __restrict__ pred,
    const unsigned* __restrict__ off, const float4* __restrict__ srt,
    float* __restrict__ bsum)
{
    const int tid   = threadIdx.x;
    const int lane8 = tid & 7;
    const int g     = blockIdx.x * 32 + (tid >> 3);   // 0..32767
    const int dir   = g >> 14;
    const int qi    = g & (NPTS - 1);

    const float* __restrict__ qp      = dir ? real : pred;
    const unsigned* __restrict__ offr = off + dir * (NC + 1);
    const float4* __restrict__ refs   = srt + dir * NPTS;

    const float qx = qp[3 * qi], qy = qp[3 * qi + 1], qz = qp[3 * qi + 2];
    const int qcx = clampi((int)(qx * INV_CELL), 0, G - 1);
    const int qcy = clampi((int)(qy * INV_CELL), 0, G - 1);
    const int qcz = clampi((int)(qz * INV_CELL), 0, G - 1);

    float best = INFINITY;
    int k = 1;
    for (;;) {
        float b = INFINITY;
        const int z0 = clampi(qcz - k, 0, G - 1), z1 = clampi(qcz + k, 0, G - 1);
        const int y0 = clampi(qcy - k, 0, G - 1), y1 = clampi(qcy + k, 0, G - 1);
        const int x0 = clampi(qcx - k, 0, G - 1), x1 = clampi(qcx + k, 0, G - 1);
        for (int cz = z0; cz <= z1; ++cz) {
            for (int cy = y0; cy <= y1; ++cy) {
                const int rowc = (cz * G + cy) * G;
                for (int cx = x0; cx <= x1; ++cx) {
                    const int c = rowc + cx;
                    const unsigned s = offr[c];
                    const unsigned e = offr[c + 1];
                    for (unsigned i = s + lane8; i < e; i += 8) {
                        const float4 r = refs[i];
                        const float dx = qx - r.x;
                        const float dy = qy - r.y;
                        const float dz = qz - r.z;
                        b = fminf(b, fmaf(dx, dx, fmaf(dy, dy, dz * dz)));
                    }
                }
            }
        }
        // 8-lane group min (bits 0..2 stay inside the group).
        b = fminf(b, __shfl_xor(b, 1, 64));
        b = fminf(b, __shfl_xor(b, 2, 64));
        b = fminf(b, __shfl_xor(b, 4, 64));
        best = fminf(best, b);
        const float reach = CELL * (float)k;
        if (best <= reach * reach || k >= G) break;   // outside pts are > 8k away
        ++k;                                          // expand (P ~ 6e-8/query)
    }

    // Deterministic per-block partial sum of sqrt(best) over 32 groups.
    __shared__ float gs[32];
    if (lane8 == 0) gs[tid >> 3] = sqrtf(best);
    __syncthreads();
    if (tid == 0) {
        float s = 0.0f;
        for (int j = 0; j < 32; ++j) s += gs[j];
        bsum[blockIdx.x] = s;
    }
}

__global__ __launch_bounds__(1024) void sum_kernel(
    const float* __restrict__ bsum, float* __restrict__ out)
{
    const int tid = threadIdx.x;
    float s = bsum[tid];                              // exactly 1024 partials
#pragma unroll
    for (int o = 32; o > 0; o >>= 1)
        s += __shfl_down(s, o, 64);
    __shared__ float red[16];
    const int wave = tid >> 6, lane = tid & 63;
    if (lane == 0) red[wave] = s;
    __syncthreads();
    if (tid < 16) {
        float v = red[tid];
#pragma unroll
        for (int o = 8; o > 0; o >>= 1)
            v += __shfl_down(v, o, 16);
        if (tid == 0) out[0] = v * (1.0f / (float)(2 * NPTS));
    }
}

extern "C" void kernel_launch(void* const* d_in, const int* in_sizes, int n_in,
                              void* d_out, int out_size, void* d_ws, size_t ws_size,
                              hipStream_t stream)
{
    const float* real_pts = (const float*)d_in[0];
    const float* pred_pts = (const float*)d_in[1];
    float* out = (float*)d_out;
    unsigned* W = (unsigned*)d_ws;

    unsigned* hist = W + W_HIST;
    unsigned* off  = W + W_OFF;
    unsigned* cur  = W + W_CUR;
    float4*   srt  = (float4*)(W + W_SRT);
    float*    bsum = (float*)(W + W_BSUM);

    init_kernel   <<<2 * NC / 256, 256, 0, stream>>>(W);
    hist_kernel   <<<2 * NPTS / 256, 256, 0, stream>>>(real_pts, pred_pts, hist);
    scan_kernel   <<<1, 1024, 0, stream>>>(hist, off, cur);
    scatter_kernel<<<2 * NPTS / 256, 256, 0, stream>>>(real_pts, pred_pts, cur, srt);
    nn_kernel     <<<2 * NPTS / 32, 256, 0, stream>>>(real_pts, pred_pts, off, srt, bsum);
    sum_kernel    <<<1, 1024, 0, stream>>>(bsum, out);
}